// Round 2
// baseline (494.659 us; speedup 1.0000x reference)
//
#include <hip/hip_runtime.h>
#include <cstdint>
#include <cstddef>

#define K_CODES 1024
#define D_DIM   64
#define B_SZ    16
#define C_SZ    64
#define T_SZ    2048
#define N_ROWS  (B_SZ * T_SZ)        // 32768
#define BCT     (B_SZ * C_SZ * T_SZ) // 2097152

// ws layout (bytes):
//   [0,      131072): idx[N_ROWS] int
//   [131072, 135168): hist[K_CODES] int        (zeroed per launch)
//   [135168, 151552): part[2048] double        (fully overwritten)
//   [151552, 155648): esq[K_CODES] float       (fully overwritten)

__global__ __launch_bounds__(256) void k_esq(const float* __restrict__ w,
                                             float* __restrict__ esq) {
    int k = blockIdx.x * blockDim.x + threadIdx.x;
    if (k >= K_CODES) return;
    const float* wr = w + (size_t)k * D_DIM;
    double s = 0.0;
#pragma unroll
    for (int d = 0; d < D_DIM; ++d) {
        double v = (double)wr[d];
        s = fma(v, v, s);
    }
    esq[k] = (float)s;
}

__global__ __launch_bounds__(256) void k_argmin(const float* __restrict__ in,
                                                const float* __restrict__ w,
                                                const float* __restrict__ esq,
                                                int* __restrict__ idx_out,
                                                int* __restrict__ hist,
                                                float* __restrict__ enc_out) {
    __shared__ float sm1[4][64];
    __shared__ float sm2[4][64];
    __shared__ int   si1[4][64];
    __shared__ int   si2[4][64];

    const int tid  = threadIdx.x;
    const int lane = tid & 63;
    const int wv   = tid >> 6;          // wave id 0..3 -> k range
    const int n    = blockIdx.x * 64 + lane;
    const int b    = n >> 11;           // / T_SZ
    const int t    = n & (T_SZ - 1);
    const size_t base = (size_t)b * C_SZ * T_SZ + (size_t)t;

    // load row, pre-scale by -2 (exact power-of-2 scaling)
    float m2x[D_DIM];
#pragma unroll
    for (int d = 0; d < D_DIM; ++d)
        m2x[d] = -2.0f * in[base + (size_t)d * T_SZ];

    float m1 = 1e30f, m2v = 1e30f;
    int   i1 = 0,     i2  = 0;
    const int kbase = wv * 256;

    for (int kk = 0; kk < 256; ++kk) {
        const int k = kbase + kk;
        const float* wr = w + (size_t)k * D_DIM;   // wave-uniform -> scalar loads
        // dual accumulators: 32-deep dep chain instead of 64 (issue-bound
        // at 2 waves/SIMD). fp32 order change is safe: final pick is the
        // fp64 top-2 recheck below.
        float acc0 = esq[k], acc1 = 0.0f;
#pragma unroll
        for (int d = 0; d < D_DIM; d += 2) {
            acc0 = fmaf(m2x[d],     wr[d],     acc0);
            acc1 = fmaf(m2x[d + 1], wr[d + 1], acc1);
        }
        const float acc = acc0 + acc1;
        if (acc < m1)       { m2v = m1; i2 = i1; m1 = acc; i1 = k; }
        else if (acc < m2v) { m2v = acc; i2 = k; }
    }

    sm1[wv][lane] = m1;  sm2[wv][lane] = m2v;
    si1[wv][lane] = i1;  si2[wv][lane] = i2;
    __syncthreads();

    if (wv == 0) {
        // merge top-2 across the 4 waves (k ranges increase with s ->
        // strict '<' keeps lowest index on ties, matching jnp.argmin)
        for (int s = 1; s < 4; ++s) {
            const float b1 = sm1[s][lane], b2 = sm2[s][lane];
            const int   j1 = si1[s][lane], j2 = si2[s][lane];
            if (b1 < m1) {
                m2v = (b2 < m1) ? b2 : m1;
                i2  = (b2 < m1) ? j2 : i1;
                m1 = b1; i1 = j1;
            } else if (b1 < m2v) {
                m2v = b1; i2 = j1;
            }
        }

        // fp64 recheck of the two candidates (decides like a float64 reference)
        const float* w1 = w + (size_t)i1 * D_DIM;
        const float* w2 = w + (size_t)i2 * D_DIM;
        double v1 = 0.0, v2 = 0.0;
#pragma unroll
        for (int d = 0; d < D_DIM; ++d) {
            const double x = -0.5 * (double)m2x[d];   // exact recovery of x
            const double a = (double)w1[d];
            const double c = (double)w2[d];
            v1 += a * (a - 2.0 * x);
            v2 += c * (c - 2.0 * x);
        }
        int fin;
        if (v1 < v2)      fin = i1;
        else if (v2 < v1) fin = i2;
        else              fin = (i1 < i2) ? i1 : i2;

        idx_out[n] = fin;
        atomicAdd(&hist[fin], 1);
        enc_out[(size_t)n * K_CODES + (size_t)fin] = 1.0f;
    }
}

__global__ __launch_bounds__(256) void k_quant(const float* __restrict__ in,
                                               const float* __restrict__ w,
                                               const int* __restrict__ idx,
                                               float* __restrict__ qout,
                                               double* __restrict__ part) {
    const int tid = threadIdx.x;
    const size_t i0 = ((size_t)blockIdx.x * 256 + (size_t)tid) * 4;

    const float4 xv = *(const float4*)(in + i0);
    const int t = (int)(i0 & (size_t)(T_SZ - 1));
    const int c = (int)((i0 >> 11) & 63);
    const int b = (int)(i0 >> 17);

    const int4 iv = *(const int4*)(idx + b * T_SZ + t);
    const float q0 = w[(size_t)iv.x * D_DIM + c];
    const float q1 = w[(size_t)iv.y * D_DIM + c];
    const float q2 = w[(size_t)iv.z * D_DIM + c];
    const float q3 = w[(size_t)iv.w * D_DIM + c];

    // straight-through value: x + (q - x), mimic reference fp32 rounding
    const float d0 = q0 - xv.x, d1 = q1 - xv.y, d2 = q2 - xv.z, d3 = q3 - xv.w;
    // qout is at +1 float offset in d_out -> not 16B aligned; scalar stores
    qout[i0 + 0] = xv.x + d0;
    qout[i0 + 1] = xv.y + d1;
    qout[i0 + 2] = xv.z + d2;
    qout[i0 + 3] = xv.w + d3;

    double sq = (double)d0 * (double)d0 + (double)d1 * (double)d1
              + (double)d2 * (double)d2 + (double)d3 * (double)d3;

    __shared__ double red[256];
    red[tid] = sq;
    __syncthreads();
#pragma unroll
    for (int st = 128; st > 0; st >>= 1) {
        if (tid < st) red[tid] += red[tid + st];
        __syncthreads();
    }
    if (tid == 0) part[blockIdx.x] = red[0];
}

__global__ __launch_bounds__(256) void k_final(const int* __restrict__ hist,
                                               const double* __restrict__ part,
                                               float* __restrict__ out_loss,
                                               float* __restrict__ out_perp) {
    __shared__ double red[256];
    const int tid = threadIdx.x;

    double s = 0.0;
    for (int i = tid; i < 2048; i += 256) s += part[i];
    red[tid] = s;
    __syncthreads();
#pragma unroll
    for (int st = 128; st > 0; st >>= 1) {
        if (tid < st) red[tid] += red[tid + st];
        __syncthreads();
    }
    const double lsum = red[0];
    __syncthreads();

    double h = 0.0;
    for (int k = tid; k < K_CODES; k += 256) {
        const double p = (double)hist[k] / (double)N_ROWS;
        h += p * log(p + 1e-10);
    }
    red[tid] = h;
    __syncthreads();
#pragma unroll
    for (int st = 128; st > 0; st >>= 1) {
        if (tid < st) red[tid] += red[tid + st];
        __syncthreads();
    }
    if (tid == 0) {
        const double mean = lsum / (double)BCT;
        out_loss[0] = (float)(1.25 * mean);   // q_latent + 0.25 * e_latent, same value
        out_perp[0] = (float)exp(-red[0]);
    }
}

extern "C" void kernel_launch(void* const* d_in, const int* in_sizes, int n_in,
                              void* d_out, int out_size, void* d_ws, size_t ws_size,
                              hipStream_t stream) {
    const float* in = (const float*)d_in[0];
    const float* w  = (const float*)d_in[1];

    float* out      = (float*)d_out;
    float* out_loss = out;                 // [0]
    float* out_q    = out + 1;             // [1, 1+BCT)
    float* out_perp = out + 1 + BCT;       // [1+BCT]
    float* out_enc  = out + 2 + BCT;       // [2+BCT, 2+BCT+N*K)

    char*   ws      = (char*)d_ws;
    int*    ws_idx  = (int*)ws;
    int*    ws_hist = (int*)(ws + 131072);
    double* ws_part = (double*)(ws + 135168);
    float*  ws_esq  = (float*)(ws + 151552);

    hipMemsetAsync(out_enc, 0, (size_t)N_ROWS * K_CODES * sizeof(float), stream);
    hipMemsetAsync(ws_hist, 0, K_CODES * sizeof(int), stream);

    k_esq   <<<4,    256, 0, stream>>>(w, ws_esq);
    k_argmin<<<512,  256, 0, stream>>>(in, w, ws_esq, ws_idx, ws_hist, out_enc);
    k_quant <<<2048, 256, 0, stream>>>(in, w, ws_idx, out_q, ws_part);
    k_final <<<1,    256, 0, stream>>>(ws_hist, ws_part, out_loss, out_perp);
}

// Round 3
// 277.371 us; speedup vs baseline: 1.7834x; 1.7834x over previous
//
#include <hip/hip_runtime.h>
#include <cstdint>
#include <cstddef>

#define K_CODES 1024
#define D_DIM   64
#define T_SZ    2048
#define N_ROWS  32768
#define BCT     2097152

typedef const __attribute__((address_space(1))) uint32_t* gp1_t;
typedef __attribute__((address_space(3))) uint32_t*       lp3_t;

// ws layout (bytes):
//   [0,    4096): hist[1024] int     (memset 0 per launch, with loss)
//   [4096, 4104): loss_sum double    (memset 0 per launch)
//   [8192, 12288): esq[1024] float   (fully overwritten by k_esq)

__global__ __launch_bounds__(256) void k_esq(const float* __restrict__ w,
                                             float* __restrict__ esq) {
    int k = blockIdx.x * blockDim.x + threadIdx.x;
    if (k >= K_CODES) return;
    const float* wr = w + (size_t)k * D_DIM;
    double s = 0.0;
#pragma unroll
    for (int d = 0; d < D_DIM; ++d) {
        double v = (double)wr[d];
        s = fma(v, v, s);
    }
    esq[k] = (float)s;
}

// One mega-kernel: argmin over 1024 codes + one-hot encodings (full rows)
// + straight-through quant output + fp64 loss partial + histogram.
// Block: 512 threads = 8 waves. lane = row (64 rows/block), wave w owns
// codes [w*128, w*128+128). Grid 512 = 2 blocks/CU (LDS-limited).
__global__ __launch_bounds__(512, 4) void k_argmin(
        const float* __restrict__ in, const float* __restrict__ w,
        const float* __restrict__ esq, int* __restrict__ hist,
        double* __restrict__ loss_sum, float* __restrict__ qout,
        float* __restrict__ enc) {
    __shared__ float lds_w[2][8192];       // 2 x 32KB: 8 waves x 16 codes x 64 f
    __shared__ float lds_esq[K_CODES];     // 4KB
    __shared__ float sm1[8][64], sm2[8][64];
    __shared__ int   si1[8][64], si2[8][64];
    __shared__ int   fin_s[64];
    __shared__ double redd[8];

    const int tid  = threadIdx.x;
    const int lane = tid & 63;
    const int wv   = tid >> 6;
    const int n    = blockIdx.x * 64 + lane;   // this lane's row
    const int b    = n >> 11;
    const int t    = n & (T_SZ - 1);
    const size_t base = (size_t)b * (D_DIM * T_SZ) + (size_t)t;

    // esq -> LDS (broadcast-read later)
    lds_esq[tid] = esq[tid];
    lds_esq[tid + 512] = esq[tid + 512];

    // row, pre-scaled by -2 (exact pow2); kept fully register-resident
    float m2x[D_DIM];
#pragma unroll
    for (int d = 0; d < D_DIM; ++d)
        m2x[d] = -2.0f * in[base + (size_t)d * T_SZ];

    // ---- stage chunk 0 ----
    // chunk c: for each wave-slice wsel, codes wsel*128+c*16 .. +16 (4KB),
    // LDS linear so global_load_lds (uniform base + lane*16) lands right.
#define STAGE(CBUF, CC)                                                        \
    {                                                                          \
        _Pragma("unroll")                                                      \
        for (int r = 0; r < 4; ++r) {                                          \
            const int li    = r * 512 + tid;                                   \
            const int wsel  = li >> 8;                                         \
            const int inner = li & 255;                                        \
            const float* g = w + (((size_t)(wsel * 128 + (CC) * 16)) << 6)     \
                               + (size_t)inner * 4;                            \
            float* l = &lds_w[CBUF][li * 4];                                   \
            __builtin_amdgcn_global_load_lds((gp1_t)g, (lp3_t)l, 16, 0, 0);    \
        }                                                                      \
    }

    STAGE(0, 0)
    __syncthreads();

    float m1 = 1e30f, m2v = 1e30f;
    int   i1 = 0,     i2  = 0;
    int   buf = 0;

    for (int c = 0; c < 8; ++c) {
        if (c < 7) STAGE(buf ^ 1, c + 1)
        const int kb = wv * 128 + c * 16;
#pragma unroll 2
        for (int kk = 0; kk < 16; ++kk) {
            const int k = kb + kk;
            const float4* wrow = (const float4*)&lds_w[buf][(wv * 16 + kk) * 64];
            float a0 = lds_esq[k], a1 = 0.f, a2 = 0.f, a3 = 0.f;
#pragma unroll
            for (int d4 = 0; d4 < 16; ++d4) {
                const float4 wv4 = wrow[d4];
                a0 = fmaf(m2x[4 * d4 + 0], wv4.x, a0);
                a1 = fmaf(m2x[4 * d4 + 1], wv4.y, a1);
                a2 = fmaf(m2x[4 * d4 + 2], wv4.z, a2);
                a3 = fmaf(m2x[4 * d4 + 3], wv4.w, a3);
            }
            const float acc = (a0 + a1) + (a2 + a3);
            if (acc < m1)       { m2v = m1; i2 = i1; m1 = acc; i1 = k; }
            else if (acc < m2v) { m2v = acc; i2 = k; }
        }
        __syncthreads();   // drains stage vmcnt + protects buf swap
        buf ^= 1;
    }

    sm1[wv][lane] = m1;  sm2[wv][lane] = m2v;
    si1[wv][lane] = i1;  si2[wv][lane] = i2;
    __syncthreads();

    if (wv == 0) {
        // merge top-2 across 8 waves (ascending k ranges; strict '<'
        // keeps lowest index on ties, matching jnp.argmin)
        for (int s = 1; s < 8; ++s) {
            const float b1 = sm1[s][lane], b2 = sm2[s][lane];
            const int   j1 = si1[s][lane], j2 = si2[s][lane];
            if (b1 < m1) {
                m2v = (b2 < m1) ? b2 : m1;
                i2  = (b2 < m1) ? j2 : i1;
                m1 = b1; i1 = j1;
            } else if (b1 < m2v) {
                m2v = b1; i2 = j1;
            }
        }
        // fp64 recheck of the two candidates (float64-reference decision)
        const float* w1 = w + ((size_t)i1 << 6);
        const float* w2 = w + ((size_t)i2 << 6);
        double v1 = 0.0, v2 = 0.0;
#pragma unroll
        for (int d = 0; d < D_DIM; ++d) {
            const double x = -0.5 * (double)m2x[d];
            const double a = (double)w1[d];
            const double cc = (double)w2[d];
            v1 += a * (a - 2.0 * x);
            v2 += cc * (cc - 2.0 * x);
        }
        int fin;
        if (v1 < v2)      fin = i1;
        else if (v2 < v1) fin = i2;
        else              fin = (i1 < i2) ? i1 : i2;

        fin_s[lane] = fin;
        atomicAdd(&hist[fin], 1);
    }
    __syncthreads();

    // ---- fused epilogue ----
    // (a) quant straight-through + fp64 loss partial.
    //     lane's own row; wave w covers c in [w*8, w*8+8) -> compile-time
    //     m2x indices via switch (rule #20: no runtime-indexed reg array).
    const int f_own = fin_s[lane];
    const float* wr = w + ((size_t)f_own << 6);
    float* qbase = qout + (size_t)b * (D_DIM * T_SZ) + (size_t)t;
    double sq = 0.0;

#define QS(C, Q)                                                               \
    {                                                                          \
        const float x  = -0.5f * m2x[C];                                       \
        const float dq = (Q)-x;                                                \
        qbase[(size_t)(C)*T_SZ] = x + dq;                                      \
        const double dd = (double)dq;                                          \
        sq = fma(dd, dd, sq);                                                  \
    }
#define QCASE(W)                                                               \
    {                                                                          \
        const float4 qa = *(const float4*)(wr + (W)*8);                        \
        const float4 qb = *(const float4*)(wr + (W)*8 + 4);                    \
        QS((W)*8 + 0, qa.x) QS((W)*8 + 1, qa.y)                                \
        QS((W)*8 + 2, qa.z) QS((W)*8 + 3, qa.w)                                \
        QS((W)*8 + 4, qb.x) QS((W)*8 + 5, qb.y)                                \
        QS((W)*8 + 6, qb.z) QS((W)*8 + 7, qb.w)                                \
    }
    switch (wv) {
        case 0: QCASE(0) break;  case 1: QCASE(1) break;
        case 2: QCASE(2) break;  case 3: QCASE(3) break;
        case 4: QCASE(4) break;  case 5: QCASE(5) break;
        case 6: QCASE(6) break;  case 7: QCASE(7) break;
    }

    // block-reduce the loss partial, one f64 atomic per block
    for (int off = 32; off > 0; off >>= 1) sq += __shfl_down(sq, off);
    if (lane == 0) redd[wv] = sq;

    // (b) full one-hot rows (replaces the 134MB memset): wave w writes
    //     rows w*8..w*8+8; float2 stores (enc base is 8B- not 16B-aligned)
#pragma unroll 1
    for (int rr = 0; rr < 8; ++rr) {
        const int row = wv * 8 + rr;
        const int f = fin_s[row];
        float* ebase = enc + (((size_t)(blockIdx.x * 64 + row)) << 10);
#pragma unroll
        for (int j = 0; j < 8; ++j) {
            const int col = j * 128 + lane * 2;
            float2 v;
            v.x = (col == f)     ? 1.0f : 0.0f;
            v.y = (col + 1 == f) ? 1.0f : 0.0f;
            *(float2*)(ebase + col) = v;
        }
    }

    __syncthreads();
    if (tid == 0) {
        double s = 0.0;
#pragma unroll
        for (int i = 0; i < 8; ++i) s += redd[i];
        atomicAdd(loss_sum, s);
    }
}

__global__ __launch_bounds__(256) void k_final(const int* __restrict__ hist,
                                               const double* __restrict__ loss_sum,
                                               float* __restrict__ out_loss,
                                               float* __restrict__ out_perp) {
    __shared__ double red[256];
    const int tid = threadIdx.x;
    double h = 0.0;
    for (int k = tid; k < K_CODES; k += 256) {
        const double p = (double)hist[k] / (double)N_ROWS;
        h += p * log(p + 1e-10);
    }
    red[tid] = h;
    __syncthreads();
#pragma unroll
    for (int st = 128; st > 0; st >>= 1) {
        if (tid < st) red[tid] += red[tid + st];
        __syncthreads();
    }
    if (tid == 0) {
        out_perp[0] = (float)exp(-red[0]);
        const double mean = loss_sum[0] / (double)BCT;
        out_loss[0] = (float)(1.25 * mean);  // q_latent + 0.25*e_latent
    }
}

extern "C" void kernel_launch(void* const* d_in, const int* in_sizes, int n_in,
                              void* d_out, int out_size, void* d_ws, size_t ws_size,
                              hipStream_t stream) {
    const float* in = (const float*)d_in[0];
    const float* w  = (const float*)d_in[1];

    float* out      = (float*)d_out;
    float* out_loss = out;                 // [0]
    float* out_q    = out + 1;             // [1, 1+BCT)
    float* out_perp = out + 1 + BCT;       // [1+BCT]
    float* out_enc  = out + 2 + BCT;       // [2+BCT, ...)

    char*   ws       = (char*)d_ws;
    int*    ws_hist  = (int*)ws;
    double* ws_loss  = (double*)(ws + 4096);
    float*  ws_esq   = (float*)(ws + 8192);

    hipMemsetAsync(ws, 0, 4104, stream);   // hist + loss_sum

    k_esq   <<<4,   256, 0, stream>>>(w, ws_esq);
    k_argmin<<<512, 512, 0, stream>>>(in, w, ws_esq, ws_hist, ws_loss,
                                      out_q, out_enc);
    k_final <<<1,   256, 0, stream>>>(ws_hist, ws_loss, out_loss, out_perp);
}